// Round 10
// baseline (112.077 us; speedup 1.0000x reference)
//
#include <hip/hip_runtime.h>
#include <math.h>

typedef __attribute__((ext_vector_type(8))) short bf16x8;
typedef __attribute__((ext_vector_type(16))) float fx16;

#define SEQ 2048
#define HD 64

// ---------- helpers ----------
__device__ __forceinline__ unsigned f2bf_bits(float f){
  unsigned u = __float_as_uint(f);
  return (u + 0x7fffu + ((u >> 16) & 1u)) >> 16;   // RNE to bf16
}
__device__ __forceinline__ unsigned cvt_pk_bf16(float a, float b){
  unsigned r;
  asm("v_cvt_pk_bf16_f32 %0, %1, %2" : "=v"(r) : "v"(a), "v"(b));
  return r;  // [15:0]=bf16(a), [31:16]=bf16(b)
}
__device__ __forceinline__ float lo16f(unsigned u){ return __uint_as_float(u << 16); }
__device__ __forceinline__ float hi16f(unsigned u){ return __uint_as_float(u & 0xffff0000u); }
union U8 { bf16x8 v; short s[8]; unsigned u[4]; };

__device__ __forceinline__ fx16 mfma_bf16(bf16x8 a, bf16x8 b, fx16 c){
  return __builtin_amdgcn_mfma_f32_32x32x16_bf16(a, b, c, 0, 0, 0);
}
__device__ __forceinline__ fx16 fzero(){
  fx16 z;
#pragma unroll
  for (int i = 0; i < 16; ++i) z[i] = 0.f;
  return z;
}

// ---------- W -> MFMA B-fragment layout ----------
// group gid = (stage*6 + t)*2 + half, stage 0..63 (k=16 each), t = n-tile 0..5.
// Lane (l31,h): col n=t*32+l31, k = stage*16 + h*8 + i.
__global__ __launch_bounds__(256) void wconv_kernel(
    const float* __restrict__ Wq, const float* __restrict__ Wk, const float* __restrict__ Wv,
    short* __restrict__ wsB)
{
  int gid = blockIdx.x * 4 + (threadIdx.x >> 6);  // 0..767
  int lane = threadIdx.x & 63;
  int l31 = lane & 31, h = lane >> 5;
  int half = gid & 1;
  int rem = gid >> 1;            // stage*6 + t
  int t = rem % 6;
  int stage = rem / 6;           // 0..63
  int n = t * 32 + l31;
  int mat = n >> 6, col = n & 63;
  const float* W = (mat == 0) ? Wq : (mat == 1) ? Wk : Wv;
  int kbase = stage * 16 + h * 8;
  U8 o;
#pragma unroll
  for (int i = 0; i < 8; ++i) {
    float f = W[(size_t)(kbase + i) * 64 + col];
    unsigned hb = f2bf_bits(f);
    if (half == 0) o.s[i] = (short)hb;
    else {
      float hf = __uint_as_float(hb << 16);
      o.s[i] = (short)f2bf_bits(f - hf);
    }
  }
  *(bf16x8*)(wsB + (size_t)gid * 512 + lane * 8) = o.v;
}

// ---------- QKV projection: BM=64, 2-m register blocking, 8 waves, grid 256 ----------
// wave w: ksel = w>>1 (K quarter), nsel = w&1 (3 n-tiles). Each B-frag reused for 2 m.
__global__ __launch_bounds__(512) void proj_kernel(
    const float* __restrict__ x, const short* __restrict__ wsB,
    short* __restrict__ qh, short* __restrict__ ql,
    short* __restrict__ kh, short* __restrict__ kl,
    short* __restrict__ vth, short* __restrict__ vtl)
{
  __shared__ float Rx[2][6144];   // 2 x 24KB reduce slots; Rx[0] reused as Vb[64][68]

  const int tid = threadIdx.x;
  const int lane = tid & 63, w = tid >> 6;   // w 0..7
  const int l31 = lane & 31, h = lane >> 5;
  const int ksel = w >> 1;                   // 0..3
  const int nsel = w & 1;                    // 0..1
  const int row0 = blockIdx.x * 64;
  const size_t xb0 = (size_t)(row0 + l31) * 1024;
  const size_t xb1 = (size_t)(row0 + 32 + l31) * 1024;

  fx16 a0[3], a1[3];   // [n-tile] for m=0 / m=1
#pragma unroll
  for (int t = 0; t < 3; ++t) { a0[t] = fzero(); a1[t] = fzero(); }

#pragma unroll 2
  for (int s = 0; s < 16; ++s) {
    const int stage = ksel * 16 + s;
    const int k = stage * 16 + h * 8;
    float4 fa0 = *(const float4*)(x + xb0 + k);
    float4 fb0 = *(const float4*)(x + xb0 + k + 4);
    float4 fa1 = *(const float4*)(x + xb1 + k);
    float4 fb1 = *(const float4*)(x + xb1 + k + 4);
    U8 ah0, al0, ah1, al1;
    ah0.u[0] = cvt_pk_bf16(fa0.x, fa0.y);
    ah0.u[1] = cvt_pk_bf16(fa0.z, fa0.w);
    ah0.u[2] = cvt_pk_bf16(fb0.x, fb0.y);
    ah0.u[3] = cvt_pk_bf16(fb0.z, fb0.w);
    al0.u[0] = cvt_pk_bf16(fa0.x - lo16f(ah0.u[0]), fa0.y - hi16f(ah0.u[0]));
    al0.u[1] = cvt_pk_bf16(fa0.z - lo16f(ah0.u[1]), fa0.w - hi16f(ah0.u[1]));
    al0.u[2] = cvt_pk_bf16(fb0.x - lo16f(ah0.u[2]), fb0.y - hi16f(ah0.u[2]));
    al0.u[3] = cvt_pk_bf16(fb0.z - lo16f(ah0.u[3]), fb0.w - hi16f(ah0.u[3]));
    ah1.u[0] = cvt_pk_bf16(fa1.x, fa1.y);
    ah1.u[1] = cvt_pk_bf16(fa1.z, fa1.w);
    ah1.u[2] = cvt_pk_bf16(fb1.x, fb1.y);
    ah1.u[3] = cvt_pk_bf16(fb1.z, fb1.w);
    al1.u[0] = cvt_pk_bf16(fa1.x - lo16f(ah1.u[0]), fa1.y - hi16f(ah1.u[0]));
    al1.u[1] = cvt_pk_bf16(fa1.z - lo16f(ah1.u[1]), fa1.w - hi16f(ah1.u[1]));
    al1.u[2] = cvt_pk_bf16(fb1.x - lo16f(ah1.u[2]), fb1.y - hi16f(ah1.u[2]));
    al1.u[3] = cvt_pk_bf16(fb1.z - lo16f(ah1.u[3]), fb1.w - hi16f(ah1.u[3]));
#pragma unroll
    for (int tt = 0; tt < 3; ++tt) {
      const int tg = nsel * 3 + tt;
      const size_t g2 = ((size_t)stage * 6 + tg) * 2;
      bf16x8 Bh = *(const bf16x8*)(wsB + g2 * 512 + lane * 8);
      bf16x8 Bl = *(const bf16x8*)(wsB + g2 * 512 + 512 + lane * 8);
      a0[tt] = mfma_bf16(al0.v, Bh, a0[tt]);
      a0[tt] = mfma_bf16(ah0.v, Bl, a0[tt]);
      a0[tt] = mfma_bf16(ah0.v, Bh, a0[tt]);
      a1[tt] = mfma_bf16(al1.v, Bh, a1[tt]);
      a1[tt] = mfma_bf16(ah1.v, Bl, a1[tt]);
      a1[tt] = mfma_bf16(ah1.v, Bh, a1[tt]);
    }
  }

  // serialized cross-ksel reduce through slot[nsel]: k3 write -> k2 += -> k1 += -> k0 read
  float* slot = &Rx[nsel][0];
  __syncthreads();
  if (ksel == 3) {
#pragma unroll
    for (int tt = 0; tt < 3; ++tt)
#pragma unroll
      for (int r = 0; r < 16; ++r) {
        slot[((tt * 2 + 0) * 16 + r) * 64 + lane] = a0[tt][r];
        slot[((tt * 2 + 1) * 16 + r) * 64 + lane] = a1[tt][r];
      }
  }
  __syncthreads();
  if (ksel == 2) {
#pragma unroll
    for (int tt = 0; tt < 3; ++tt)
#pragma unroll
      for (int r = 0; r < 16; ++r) {
        slot[((tt * 2 + 0) * 16 + r) * 64 + lane] += a0[tt][r];
        slot[((tt * 2 + 1) * 16 + r) * 64 + lane] += a1[tt][r];
      }
  }
  __syncthreads();
  if (ksel == 1) {
#pragma unroll
    for (int tt = 0; tt < 3; ++tt)
#pragma unroll
      for (int r = 0; r < 16; ++r) {
        slot[((tt * 2 + 0) * 16 + r) * 64 + lane] += a0[tt][r];
        slot[((tt * 2 + 1) * 16 + r) * 64 + lane] += a1[tt][r];
      }
  }
  __syncthreads();
  if (ksel == 0) {
#pragma unroll
    for (int tt = 0; tt < 3; ++tt)
#pragma unroll
      for (int r = 0; r < 16; ++r) {
        a0[tt][r] += slot[((tt * 2 + 0) * 16 + r) * 64 + lane];
        a1[tt][r] += slot[((tt * 2 + 1) * 16 + r) * 64 + lane];
      }
  }
  __syncthreads();

  // epilogue (ksel==0 waves): q/k direct stores, v via Vb (aliases Rx[0])
  float* Vb = &Rx[0][0];
  if (ksel == 0) {
#pragma unroll
    for (int tt = 0; tt < 3; ++tt) {
      const int tg = nsel * 3 + tt;
      const int mat = tg >> 1;
      const int colb = (tg & 1) * 32 + l31;
      if (mat < 2) {
        short* dh = (mat == 0) ? qh : kh;
        short* dl = (mat == 0) ? ql : kl;
#pragma unroll
        for (int m = 0; m < 2; ++m)
#pragma unroll
          for (int r = 0; r < 16; ++r) {
            float f = (m ? a1[tt][r] : a0[tt][r]);
            int rowg = row0 + m * 32 + (r & 3) + 8 * (r >> 2) + 4 * h;
            unsigned hb = f2bf_bits(f);
            float hf = __uint_as_float(hb << 16);
            unsigned lb = f2bf_bits(f - hf);
            dh[(size_t)rowg * 64 + colb] = (short)hb;
            dl[(size_t)rowg * 64 + colb] = (short)lb;
          }
      } else {
#pragma unroll
        for (int m = 0; m < 2; ++m)
#pragma unroll
          for (int r = 0; r < 16; ++r) {
            float f = (m ? a1[tt][r] : a0[tt][r]);
            int srel = m * 32 + (r & 3) + 8 * (r >> 2) + 4 * h;
            Vb[srel * 68 + (tg - 4) * 32 + l31] = f;
          }
      }
    }
  }
  __syncthreads();
  if (tid < 256) {
    int d = tid >> 2, sc = (tid & 3) * 16;
    int bb = row0 >> 11, s0 = row0 & 2047;
    U8 hv0, hv1, lv0, lv1;
#pragma unroll
    for (int ss = 0; ss < 16; ++ss) {
      float f = Vb[(sc + ss) * 68 + d];
      unsigned hb = f2bf_bits(f);
      float hf = __uint_as_float(hb << 16);
      unsigned lb = f2bf_bits(f - hf);
      if (ss < 8) { hv0.s[ss] = (short)hb; lv0.s[ss] = (short)lb; }
      else        { hv1.s[ss - 8] = (short)hb; lv1.s[ss - 8] = (short)lb; }
    }
    size_t o = (size_t)(bb * 64 + d) * 2048 + s0 + sc;
    *(bf16x8*)(vth + o) = hv0.v;  *(bf16x8*)(vth + o + 8) = hv1.v;
    *(bf16x8*)(vtl + o) = lv0.v;  *(bf16x8*)(vtl + o + 8) = lv1.v;
  }
}

// ---------- attention per-q-group step ----------
__device__ __forceinline__ void attn_step_qg(
    const bf16x8* __restrict__ qh_, const bf16x8* __restrict__ ql_,
    const bf16x8* __restrict__ kah, const bf16x8* __restrict__ kal,
    const bf16x8 (*vfh)[2], const bf16x8 (*vfl)[2],
    fx16& accA, fx16& accB, float& Mrun, float& lrun,
    const int kt, const int qt, const int qg, const int h, const int qabs)
{
  fx16 st = fzero();
  __builtin_amdgcn_s_setprio(1);
#pragma unroll
  for (int ds = 0; ds < 4; ++ds) {
    st = mfma_bf16(kah[ds], qh_[ds], st);
    st = mfma_bf16(kal[ds], qh_[ds], st);
    st = mfma_bf16(kah[ds], ql_[ds], st);
  }
  __builtin_amdgcn_s_setprio(0);

  float sv[16];
  const bool diag = (kt == 2 * qt + qg);
#pragma unroll
  for (int r2 = 0; r2 < 16; ++r2) {
    float s = st[r2] * 0.125f;
    if (diag) {
      int ka = kt * 32 + (r2 & 3) + 8 * (r2 >> 2) + 4 * h;
      if (ka > qabs) s = -3e38f;
    }
    sv[r2] = s;
  }
  float tm = sv[0];
#pragma unroll
  for (int r2 = 1; r2 < 16; ++r2) tm = fmaxf(tm, sv[r2]);
  tm = fmaxf(tm, __shfl_xor(tm, 32, 64));
  float Mnew = fmaxf(Mrun, tm);
  float alpha = __expf(Mrun - Mnew);
  Mrun = Mnew;
  float psum = 0.f;
#pragma unroll
  for (int r2 = 0; r2 < 16; ++r2) { sv[r2] = __expf(sv[r2] - Mnew); psum += sv[r2]; }
  psum += __shfl_xor(psum, 32, 64);
  lrun = lrun * alpha + psum;
#pragma unroll
  for (int r2 = 0; r2 < 16; ++r2) { accA[r2] *= alpha; accB[r2] *= alpha; }

  unsigned chv[8], clv[8];
#pragma unroll
  for (int q2 = 0; q2 < 8; ++q2) {
    unsigned c = cvt_pk_bf16(sv[2 * q2], sv[2 * q2 + 1]);
    chv[q2] = c;
    clv[q2] = cvt_pk_bf16(sv[2 * q2] - lo16f(c), sv[2 * q2 + 1] - hi16f(c));
  }
#pragma unroll
  for (int kp = 0; kp < 2; ++kp) {
    U8 ph, pl;
    {
      unsigned c0 = chv[4 * kp], c1 = chv[4 * kp + 1], c2 = chv[4 * kp + 2], c3 = chv[4 * kp + 3];
      unsigned x0 = (unsigned)__shfl_xor((int)c0, 32, 64);
      unsigned x1 = (unsigned)__shfl_xor((int)c1, 32, 64);
      unsigned x2 = (unsigned)__shfl_xor((int)c2, 32, 64);
      unsigned x3 = (unsigned)__shfl_xor((int)c3, 32, 64);
      ph.u[0] = h ? x2 : c0;  ph.u[1] = h ? x3 : c1;
      ph.u[2] = h ? c2 : x0;  ph.u[3] = h ? c3 : x1;
      c0 = clv[4 * kp]; c1 = clv[4 * kp + 1]; c2 = clv[4 * kp + 2]; c3 = clv[4 * kp + 3];
      x0 = (unsigned)__shfl_xor((int)c0, 32, 64);
      x1 = (unsigned)__shfl_xor((int)c1, 32, 64);
      x2 = (unsigned)__shfl_xor((int)c2, 32, 64);
      x3 = (unsigned)__shfl_xor((int)c3, 32, 64);
      pl.u[0] = h ? x2 : c0;  pl.u[1] = h ? x3 : c1;
      pl.u[2] = h ? c2 : x0;  pl.u[3] = h ? c3 : x1;
    }
    __builtin_amdgcn_s_setprio(1);
    accA = mfma_bf16(vfl[kp][0], ph.v, accA);
    accA = mfma_bf16(vfh[kp][0], pl.v, accA);
    accA = mfma_bf16(vfh[kp][0], ph.v, accA);
    accB = mfma_bf16(vfl[kp][1], ph.v, accB);
    accB = mfma_bf16(vfh[kp][1], pl.v, accB);
    accB = mfma_bf16(vfh[kp][1], ph.v, accB);
    __builtin_amdgcn_s_setprio(0);
  }
}

// ---------- Flash attention: 1 wave = 64 q-cols (2 q-groups), K-step 32 ----------
// K/V frags shared by both q-groups -> L2 traffic halved. grid 1792 = 8 x 224 segs.
__global__ __launch_bounds__(64) void attn_kernel(
    const short* __restrict__ qh, const short* __restrict__ ql,
    const short* __restrict__ kh, const short* __restrict__ kl,
    const short* __restrict__ vth, const short* __restrict__ vtl,
    float* __restrict__ segO, float* __restrict__ segL, float* __restrict__ segM)
{
  const int bid = blockIdx.x;
  const int b = bid & 7;
  int r = bid >> 3;               // 0..223
  int qt = 0, acc = 0;
  while (r >= acc + ((2 * qt + 6) / 5)) { acc += (2 * qt + 6) / 5; ++qt; }
  const int sg = r - acc;
  const int nk = 2 * qt + 2;
  const int kt0 = sg * 5;
  int nsteps = nk - kt0; if (nsteps > 5) nsteps = 5;

  const int lane = threadIdx.x;
  const int l31 = lane & 31, h = lane >> 5;
  const int qa0 = qt * 64 + l31;
  const int qa1 = qt * 64 + 32 + l31;

  bf16x8 q0h[4], q0l[4], q1h[4], q1l[4];
  {
    size_t r0 = ((size_t)b * 2048 + qt * 64 + l31) * 64 + 8 * h;
    size_t r1 = r0 + 32 * 64;
#pragma unroll
    for (int ds = 0; ds < 4; ++ds) {
      q0h[ds] = *(const bf16x8*)(qh + r0 + ds * 16);
      q0l[ds] = *(const bf16x8*)(ql + r0 + ds * 16);
      q1h[ds] = *(const bf16x8*)(qh + r1 + ds * 16);
      q1l[ds] = *(const bf16x8*)(ql + r1 + ds * 16);
    }
  }

  fx16 a00 = fzero(), a01 = fzero(), a10 = fzero(), a11 = fzero();
  float M0 = -3e38f, L0 = 0.f, M1 = -3e38f, L1 = 0.f;

  for (int it = 0; it < nsteps; ++it) {
    const int kt = kt0 + it;
    bf16x8 kah[4], kal[4];
    {
      const size_t koff = ((size_t)b * 2048 + (size_t)kt * 32 + l31) * 64 + 8 * h;
#pragma unroll
      for (int ds = 0; ds < 4; ++ds) {
        kah[ds] = *(const bf16x8*)(kh + koff + ds * 16);
        kal[ds] = *(const bf16x8*)(kl + koff + ds * 16);
      }
    }
    bf16x8 vfh[2][2], vfl[2][2];
#pragma unroll
    for (int kp = 0; kp < 2; ++kp)
#pragma unroll
      for (int md = 0; md < 2; ++md) {
        const size_t vrow = (size_t)(b * 64 + md * 32 + l31) * 2048 + kt * 32 + kp * 16 + 8 * h;
        vfh[kp][md] = *(const bf16x8*)(vth + vrow);
        vfl[kp][md] = *(const bf16x8*)(vtl + vrow);
      }

    if (kt <= 2 * qt)
      attn_step_qg(q0h, q0l, kah, kal, vfh, vfl, a00, a01, M0, L0, kt, qt, 0, h, qa0);
    attn_step_qg(q1h, q1l, kah, kal, vfh, vfl, a10, a11, M1, L1, kt, qt, 1, h, qa1);
  }

  // write seg partials: O^T [64 d][64 q] + l,m per q
  float* o = segO + (size_t)bid * 4096;
#pragma unroll
  for (int r2 = 0; r2 < 16; ++r2) {
    int d0 = (r2 & 3) + 8 * (r2 >> 2) + 4 * h;
    o[d0 * 64 + l31]             = a00[r2];
    o[(32 + d0) * 64 + l31]      = a01[r2];
    o[d0 * 64 + 32 + l31]        = a10[r2];
    o[(32 + d0) * 64 + 32 + l31] = a11[r2];
  }
  if (h == 0) {
    segL[(size_t)bid * 64 + l31]      = L0;
    segL[(size_t)bid * 64 + 32 + l31] = L1;
    segM[(size_t)bid * 64 + l31]      = M0;
    segM[(size_t)bid * 64 + 32 + l31] = M1;
  }
}

// ---------- combine: merge <=13 segs per (b, qt64), normalize, transpose, write ----------
__global__ __launch_bounds__(256) void combine_kernel(
    const float* __restrict__ segO, const float* __restrict__ segL,
    const float* __restrict__ segM, float* __restrict__ out)
{
  __shared__ float Sc[13][64];
  __shared__ float Linv[64];
  __shared__ float Ot[64 * 68];

  const int bq = blockIdx.x;            // 0..255
  const int b = bq >> 5, qt = bq & 31;
  const int nsg = (2 * qt + 6) / 5;
  int base = 0;
  for (int i = 0; i < qt; ++i) base += (2 * i + 6) / 5;
  const int tid = threadIdx.x;

  if (tid < 64) {
    float M = -3e38f;
    for (int s = 0; s < nsg; ++s)
      M = fmaxf(M, segM[(size_t)((base + s) * 8 + b) * 64 + tid]);
    float L = 0.f;
    for (int s = 0; s < nsg; ++s) {
      float e = __expf(segM[(size_t)((base + s) * 8 + b) * 64 + tid] - M);
      Sc[s][tid] = e;
      L += e * segL[(size_t)((base + s) * 8 + b) * 64 + tid];
    }
    Linv[tid] = 1.f / L;
  }
  __syncthreads();
  {
    for (int i = tid; i < 1024; i += 256) {
      int d = i >> 4, q4 = (i & 15) * 4;
      float4 a = {0.f, 0.f, 0.f, 0.f};
      for (int s = 0; s < nsg; ++s) {
        float4 v = *(const float4*)(segO + (size_t)((base + s) * 8 + b) * 4096 + d * 64 + q4);
        a.x += Sc[s][q4 + 0] * v.x;
        a.y += Sc[s][q4 + 1] * v.y;
        a.z += Sc[s][q4 + 2] * v.z;
        a.w += Sc[s][q4 + 3] * v.w;
      }
      *(float4*)&Ot[d * 68 + q4] = a;
    }
  }
  __syncthreads();
  {
    const int q = tid >> 2, dc = (tid & 3) * 16;
    const float inv = Linv[q];
    float* dst = out + ((size_t)b * 2048 + qt * 64 + q) * 64 + dc;
#pragma unroll
    for (int i = 0; i < 4; ++i) {
      float4 o;
      o.x = Ot[(dc + 4 * i + 0) * 68 + q] * inv;
      o.y = Ot[(dc + 4 * i + 1) * 68 + q] * inv;
      o.z = Ot[(dc + 4 * i + 2) * 68 + q] * inv;
      o.w = Ot[(dc + 4 * i + 3) * 68 + q] * inv;
      *(float4*)(dst + 4 * i) = o;
    }
  }
}

// ---------- launch ----------
extern "C" void kernel_launch(void* const* d_in, const int* in_sizes, int n_in,
                              void* d_out, int out_size, void* d_ws, size_t ws_size,
                              hipStream_t stream) {
  const float* x  = (const float*)d_in[0];
  const float* Wq = (const float*)d_in[1];
  const float* Wk = (const float*)d_in[2];
  const float* Wv = (const float*)d_in[3];

  char* wsb = (char*)d_ws;
  short* wsB = (short*)(wsb + 0);                     // 786432 B
  short* qh  = (short*)(wsb + 786432);
  short* ql  = (short*)(wsb + 2883584);
  short* kh  = (short*)(wsb + 4980736);
  short* kl  = (short*)(wsb + 7077888);
  short* vth = (short*)(wsb + 9175040);
  short* vtl = (short*)(wsb + 11272192);
  float* segO = (float*)(wsb + 13369344);             // 1792*4096*4 = 29360128 B
  float* segL = (float*)(wsb + 42729472);             // 1792*64*4 = 458752 B
  float* segM = (float*)(wsb + 43188224);             // 458752 B

  wconv_kernel<<<192, 256, 0, stream>>>(Wq, Wk, Wv, wsB);
  proj_kernel<<<256, 512, 0, stream>>>(x, wsB, qh, ql, kh, kl, vth, vtl);
  attn_kernel<<<1792, 64, 0, stream>>>(qh, ql, kh, kl, vth, vtl, segO, segL, segM);
  combine_kernel<<<256, 256, 0, stream>>>(segO, segL, segM, (float*)d_out);
}